// Round 1
// baseline (680.751 us; speedup 1.0000x reference)
//
#include <hip/hip_runtime.h>

// Output: emb[B=256][NUM_EMB=10000][D=64] fp32, zero except rows
// (bag_ids[l], input_[l]) which get weight[input_[l]] * psw[l].
//
// R1: replace hipMemsetAsync (measured ~1 TB/s effective -> 625us) with a
// custom grid-stride float4 nontemporal zero-fill (2048 blocks x 256 thr,
// saturates all 8 XCDs), then the tiny scatter kernel (3.3 MB traffic).

#define EMBED_DIM 64

typedef __attribute__((ext_vector_type(4))) float f32x4;

__global__ __launch_bounds__(256) void FullMultiEmbedding_zero(f32x4* __restrict__ out,
                                                               size_t n4,
                                                               float* __restrict__ out_tail,
                                                               int tail) {
    size_t stride = (size_t)gridDim.x * blockDim.x;
    f32x4 z = (f32x4)0.0f;
    for (size_t i = (size_t)blockIdx.x * blockDim.x + threadIdx.x; i < n4; i += stride)
        __builtin_nontemporal_store(z, out + i);
    // tail (out_size not divisible by 4) — defensive, zero for this problem
    if (blockIdx.x == 0 && (int)threadIdx.x < tail)
        out_tail[threadIdx.x] = 0.0f;
}

__global__ void FullMultiEmbedding_scatter(const int* __restrict__ input_,
                                           const int* __restrict__ offsets,
                                           const float* __restrict__ psw,
                                           const float* __restrict__ weight,
                                           float* __restrict__ out,
                                           int L, int B, int num_emb) {
    int t = blockIdx.x * blockDim.x + threadIdx.x;
    int l = t >> 4;        // sample index (one 64-float row)
    int q = t & 15;        // which float4 of the row
    if (l >= L) return;

    int idx = input_[l];

    // binary search: largest bag with offsets[bag] <= l
    int lo = 0, hi = B - 1;
    while (lo < hi) {
        int mid = (lo + hi + 1) >> 1;
        if (offsets[mid] <= l) lo = mid; else hi = mid - 1;
    }
    int bag = lo;

    float w = psw[l];
    const float4* src = (const float4*)(weight + (size_t)idx * EMBED_DIM);
    float4 v = src[q];
    v.x *= w; v.y *= w; v.z *= w; v.w *= w;

    float4* dst = (float4*)(out + ((size_t)bag * num_emb + (size_t)idx) * EMBED_DIM);
    dst[q] = v;
}

extern "C" void kernel_launch(void* const* d_in, const int* in_sizes, int n_in,
                              void* d_out, int out_size, void* d_ws, size_t ws_size,
                              hipStream_t stream) {
    const int*   input_  = (const int*)d_in[0];
    const int*   offsets = (const int*)d_in[1];
    const float* psw     = (const float*)d_in[2];
    const float* weight  = (const float*)d_in[3];
    float*       out     = (float*)d_out;

    const int L = in_sizes[0];                       // 12800
    const int B = in_sizes[1];                       // 256
    const int num_emb = in_sizes[3] / EMBED_DIM;     // 10000

    // Zero the whole output (harness re-poisons to 0xAA before every launch).
    size_t n_floats = (size_t)out_size;
    size_t n4 = n_floats >> 2;
    int tail = (int)(n_floats & 3);
    int zgrid = 2048;                                 // 8 blocks/CU, all XCDs
    size_t blocks_needed = (n4 + 255) / 256;
    if ((size_t)zgrid > blocks_needed) zgrid = (int)blocks_needed;
    FullMultiEmbedding_zero<<<zgrid, 256, 0, stream>>>(
        (f32x4*)out, n4, out + (n4 << 2), tail);

    // Scatter the 12800 weighted rows: 16 threads (float4 lanes) per sample.
    int threads = L * 16;
    int block = 256;
    int grid = (threads + block - 1) / block;
    FullMultiEmbedding_scatter<<<grid, block, 0, stream>>>(
        input_, offsets, psw, weight, out, L, B, num_emb);
}

// Round 2
// 654.682 us; speedup vs baseline: 1.0398x; 1.0398x over previous
//
#include <hip/hip_runtime.h>

// Output: emb[B=256][NUM_EMB=10000][D=64] fp32, zero except rows
// (bag_ids[l], input_[l]) which get weight[input_[l]] * psw[l].
//
// R2: custom zero-fill with PLAIN (temporal) float4 stores, contiguous
// chunk per block, 1024 blocks x 256 threads. R1's nontemporal+grid-stride
// variant ran at ~2.7 TB/s; rocclr's fillBufferAligned proves plain stores
// at modest occupancy reach 6.2 TB/s (78% peak) on this buffer.

#define EMBED_DIM 64

typedef __attribute__((ext_vector_type(4))) float f32x4;

__global__ __launch_bounds__(256) void FullMultiEmbedding_zero(f32x4* __restrict__ out,
                                                               size_t n4) {
    // Contiguous chunk per block; within the chunk, wave-contiguous stores
    // (256 threads x 16B = 4 KB per step).
    size_t per_block = (n4 + gridDim.x - 1) / gridDim.x;
    size_t begin = (size_t)blockIdx.x * per_block;
    size_t end = begin + per_block;
    if (end > n4) end = n4;
    f32x4 z = (f32x4)0.0f;
    for (size_t i = begin + threadIdx.x; i < end; i += blockDim.x)
        out[i] = z;
}

__global__ void FullMultiEmbedding_scatter(const int* __restrict__ input_,
                                           const int* __restrict__ offsets,
                                           const float* __restrict__ psw,
                                           const float* __restrict__ weight,
                                           float* __restrict__ out,
                                           int L, int B, int num_emb) {
    int t = blockIdx.x * blockDim.x + threadIdx.x;
    int l = t >> 4;        // sample index (one 64-float row)
    int q = t & 15;        // which float4 of the row
    if (l >= L) return;

    int idx = input_[l];

    // binary search: largest bag with offsets[bag] <= l
    int lo = 0, hi = B - 1;
    while (lo < hi) {
        int mid = (lo + hi + 1) >> 1;
        if (offsets[mid] <= l) lo = mid; else hi = mid - 1;
    }
    int bag = lo;

    float w = psw[l];
    const float4* src = (const float4*)(weight + (size_t)idx * EMBED_DIM);
    float4 v = src[q];
    v.x *= w; v.y *= w; v.z *= w; v.w *= w;

    float4* dst = (float4*)(out + ((size_t)bag * num_emb + (size_t)idx) * EMBED_DIM);
    dst[q] = v;
}

extern "C" void kernel_launch(void* const* d_in, const int* in_sizes, int n_in,
                              void* d_out, int out_size, void* d_ws, size_t ws_size,
                              hipStream_t stream) {
    const int*   input_  = (const int*)d_in[0];
    const int*   offsets = (const int*)d_in[1];
    const float* psw     = (const float*)d_in[2];
    const float* weight  = (const float*)d_in[3];
    float*       out     = (float*)d_out;

    const int L = in_sizes[0];                       // 12800
    const int B = in_sizes[1];                       // 256
    const int num_emb = in_sizes[3] / EMBED_DIM;     // 10000

    // Zero the whole output (harness re-poisons to 0xAA before every launch).
    size_t n_floats = (size_t)out_size;
    size_t n4 = n_floats >> 2;                       // out_size % 4 == 0 here
    int zgrid = 1024;                                // 4 blocks/CU, contiguous chunks
    size_t blocks_needed = (n4 + 255) / 256;
    if ((size_t)zgrid > blocks_needed) zgrid = (int)blocks_needed;
    FullMultiEmbedding_zero<<<zgrid, 256, 0, stream>>>((f32x4*)out, n4);

    // Scatter the 12800 weighted rows: 16 threads (float4 lanes) per sample.
    int threads = L * 16;
    int block = 256;
    int grid = (threads + block - 1) / block;
    FullMultiEmbedding_scatter<<<grid, block, 0, stream>>>(
        input_, offsets, psw, weight, out, L, B, num_emb);
}

// Round 3
// 643.271 us; speedup vs baseline: 1.0583x; 1.0177x over previous
//
#include <hip/hip_runtime.h>

// Output: emb[B=256][NUM_EMB=10000][D=64] fp32, zero except rows
// (bag_ids[l], input_[l]) which get weight[input_[l]] * psw[l].
//
// R3: zero-fill now mimics rocclr fillBufferAligned exactly: plain temporal
// float4 stores, grid-stride INTERLEAVED sweep (whole grid writes one
// contiguous 2MB window per iteration), small grid (512 blocks x 256).
// R1 (interleaved+nontemporal) = 2.7 TB/s, R2 (chunked+temporal) = 2.85 TB/s,
// rocclr (interleaved+temporal, ~200 blocks) = 6.25 TB/s on this buffer.

#define EMBED_DIM 64

typedef __attribute__((ext_vector_type(4))) float f32x4;

__global__ __launch_bounds__(256) void FullMultiEmbedding_zero(f32x4* __restrict__ out,
                                                               size_t n4,
                                                               float* __restrict__ out_tail,
                                                               int tail) {
    size_t stride = (size_t)gridDim.x * blockDim.x;
    f32x4 z = {0.0f, 0.0f, 0.0f, 0.0f};
    for (size_t i = (size_t)blockIdx.x * blockDim.x + threadIdx.x; i < n4; i += stride)
        out[i] = z;
    // tail (out_size not divisible by 4) — defensive, zero for this problem
    if (blockIdx.x == 0 && (int)threadIdx.x < tail)
        out_tail[threadIdx.x] = 0.0f;
}

__global__ void FullMultiEmbedding_scatter(const int* __restrict__ input_,
                                           const int* __restrict__ offsets,
                                           const float* __restrict__ psw,
                                           const float* __restrict__ weight,
                                           float* __restrict__ out,
                                           int L, int B, int num_emb) {
    int t = blockIdx.x * blockDim.x + threadIdx.x;
    int l = t >> 4;        // sample index (one 64-float row)
    int q = t & 15;        // which float4 of the row
    if (l >= L) return;

    int idx = input_[l];

    // binary search: largest bag with offsets[bag] <= l
    int lo = 0, hi = B - 1;
    while (lo < hi) {
        int mid = (lo + hi + 1) >> 1;
        if (offsets[mid] <= l) lo = mid; else hi = mid - 1;
    }
    int bag = lo;

    float w = psw[l];
    const float4* src = (const float4*)(weight + (size_t)idx * EMBED_DIM);
    float4 v = src[q];
    v.x *= w; v.y *= w; v.z *= w; v.w *= w;

    float4* dst = (float4*)(out + ((size_t)bag * num_emb + (size_t)idx) * EMBED_DIM);
    dst[q] = v;
}

extern "C" void kernel_launch(void* const* d_in, const int* in_sizes, int n_in,
                              void* d_out, int out_size, void* d_ws, size_t ws_size,
                              hipStream_t stream) {
    const int*   input_  = (const int*)d_in[0];
    const int*   offsets = (const int*)d_in[1];
    const float* psw     = (const float*)d_in[2];
    const float* weight  = (const float*)d_in[3];
    float*       out     = (float*)d_out;

    const int L = in_sizes[0];                       // 12800
    const int B = in_sizes[1];                       // 256
    const int num_emb = in_sizes[3] / EMBED_DIM;     // 10000

    // Zero the whole output (harness re-poisons to 0xAA before every launch).
    size_t n_floats = (size_t)out_size;
    size_t n4 = n_floats >> 2;
    int tail = (int)(n_floats & 3);
    int zgrid = 512;                                  // rocclr-like small grid
    size_t blocks_needed = (n4 + 255) / 256;
    if ((size_t)zgrid > blocks_needed) zgrid = (int)blocks_needed;
    FullMultiEmbedding_zero<<<zgrid, 256, 0, stream>>>(
        (f32x4*)out, n4, out + (n4 << 2), tail);

    // Scatter the 12800 weighted rows: 16 threads (float4 lanes) per sample.
    int threads = L * 16;
    int block = 256;
    int grid = (threads + block - 1) / block;
    FullMultiEmbedding_scatter<<<grid, block, 0, stream>>>(
        input_, offsets, psw, weight, out, L, B, num_emb);
}